// Round 1
// baseline (1763.524 us; speedup 1.0000x reference)
//
#include <hip/hip_runtime.h>
#include <math.h>

#define VSZ 50000
#define HD 600
#define HHD 300
#define LATD 100
#define MLEN 50
#define TIN 48
#define TTGT 50

__device__ __forceinline__ float sigmoidf_(float x){ return 1.0f/(1.0f+__expf(-x)); }

// zero a range
__global__ void k_zero(float* p, int n){
    int i = blockIdx.x*blockDim.x+threadIdx.x;
    if (i<n) p[i]=0.f;
}

// encoder gi = wih @ x + bih for all t, both dirs. out layout: [t][dir*900+j]
__global__ void k_enc_gi(const float* __restrict__ emb_enc, const int* __restrict__ toks,
                         const float* __restrict__ wih_f, const float* __restrict__ bih_f,
                         const float* __restrict__ wih_b, const float* __restrict__ bih_b,
                         float* __restrict__ gi){
    int idx = blockIdx.x*blockDim.x+threadIdx.x;
    if (idx >= TIN*1800) return;
    int t = idx/1800, r = idx%1800;
    int dir = r/900, j = r%900;
    const float* w = dir ? wih_b : wih_f;
    const float* b = dir ? bih_b : bih_f;
    const float* x = emb_enc + (long)toks[t]*HD;
    const float* wr = w + (long)j*HD;
    float acc = b[j];
    for (int k=0;k<HD;k+=4){
        float4 wv = *(const float4*)(wr+k);
        float4 xv = *(const float4*)(x+k);
        acc = fmaf(wv.x,xv.x,acc); acc = fmaf(wv.y,xv.y,acc);
        acc = fmaf(wv.z,xv.z,acc); acc = fmaf(wv.w,xv.w,acc);
    }
    gi[(long)t*1800 + dir*900 + j] = acc;
}

// one encoder step: 600 outputs (hf2|hb2), one wave per output
__global__ void k_enc_step(const float* __restrict__ whh_f, const float* __restrict__ bhh_f,
                           const float* __restrict__ whh_b, const float* __restrict__ bhh_b,
                           const float* __restrict__ gi_t,
                           const float* __restrict__ h_prev,   // 600 or nullptr (t==0)
                           float* __restrict__ h_out){
    int wave = (blockIdx.x*blockDim.x + threadIdx.x)>>6;
    int lane = threadIdx.x & 63;
    if (wave >= HD) return;
    int dir = wave/HHD, k = wave%HHD;
    const float* whh = dir ? whh_b : whh_f;
    const float* bhh = dir ? bhh_b : bhh_f;
    float sr=0.f, sz=0.f, sn=0.f;
    if (h_prev){
        const float* hp = h_prev + dir*HHD;
        for (int k2=lane;k2<HHD;k2+=64){
            float hv = hp[k2];
            sr = fmaf(whh[(long)k*HHD + k2], hv, sr);
            sz = fmaf(whh[(long)(HHD+k)*HHD + k2], hv, sz);
            sn = fmaf(whh[(long)(2*HHD+k)*HHD + k2], hv, sn);
        }
    }
    for (int off=32; off; off>>=1){
        sr += __shfl_xor(sr, off);
        sz += __shfl_xor(sz, off);
        sn += __shfl_xor(sn, off);
    }
    if (lane==0){
        float hpk = h_prev ? h_prev[dir*HHD + k] : 0.f;
        float r = sigmoidf_(gi_t[dir*900 + k]       + sr + bhh[k]);
        float z = sigmoidf_(gi_t[dir*900 + HHD + k] + sz + bhh[HHD+k]);
        float n = tanhf(gi_t[dir*900 + 2*HHD + k] + r*(sn + bhh[2*HHD+k]));
        h_out[dir*HHD + k] = (1.f-z)*n + z*hpk;
    }
}

// mean/logv: 2*50*100 outputs, K=600
__global__ void k_meanlogv(const float* __restrict__ enc_out,
                           const float* __restrict__ w_mean, const float* __restrict__ b_mean,
                           const float* __restrict__ w_logv, const float* __restrict__ b_logv,
                           float* __restrict__ out_mean, float* __restrict__ out_logv){
    int idx = blockIdx.x*blockDim.x+threadIdx.x;
    if (idx >= 2*MLEN*LATD) return;
    int which = idx/(MLEN*LATD);
    int rem = idx%(MLEN*LATD);
    int i = rem/LATD, l = rem%LATD;
    const float* W = which ? w_logv : w_mean;
    float acc = (which ? b_logv : b_mean)[l];
    const float* e = enc_out + (long)i*HD;
    const float* wr = W + (long)l*HD;
    for (int k=0;k<HD;k+=4){
        float4 wv = *(const float4*)(wr+k);
        float4 ev = *(const float4*)(e+k);
        acc = fmaf(wv.x,ev.x,acc); acc = fmaf(wv.y,ev.y,acc);
        acc = fmaf(wv.z,ev.z,acc); acc = fmaf(wv.w,ev.w,acc);
    }
    if (which) out_logv[rem] = acc; else out_mean[rem] = acc;
}

// z = eps*exp(0.5*logv)+mean
__global__ void k_z(const float* __restrict__ eps, const float* __restrict__ logv,
                    const float* __restrict__ mean, float* __restrict__ z){
    int i = blockIdx.x*blockDim.x+threadIdx.x;
    if (i < MLEN*LATD) z[i] = eps[i]*__expf(0.5f*logv[i]) + mean[i];
}

// latent_out[i][j] = dot(z[i,:], w_l2h[j,:]) + b_l2h[j]  (K=100)
__global__ void k_latent(const float* __restrict__ z, const float* __restrict__ w_l2h,
                         const float* __restrict__ b_l2h, float* __restrict__ lat){
    int idx = blockIdx.x*blockDim.x+threadIdx.x;
    if (idx >= MLEN*HD) return;
    int i = idx/HD, j = idx%HD;
    const float* zr = z + i*LATD;
    const float* wr = w_l2h + (long)j*LATD;
    float acc = b_l2h[j];
    for (int k=0;k<LATD;k+=4){
        float4 wv = *(const float4*)(wr+k);
        float4 zv = *(const float4*)(zr+k);
        acc = fmaf(wv.x,zv.x,acc); acc = fmaf(wv.y,zv.y,acc);
        acc = fmaf(wv.z,zv.z,acc); acc = fmaf(wv.w,zv.w,acc);
    }
    lat[(long)i*HD + j] = acc;
}

// M_comb[j][i] = dot(comb_w[j, 600:], latent_out[i,:])  (600x50 out, K=600)
__global__ void k_mcomb(const float* __restrict__ comb_w, const float* __restrict__ lat,
                        float* __restrict__ M){
    int idx = blockIdx.x*blockDim.x+threadIdx.x;
    if (idx >= HD*MLEN) return;
    int j = idx/MLEN, i = idx%MLEN;
    const float* wr = comb_w + (long)j*1200 + HD;
    const float* lr = lat + (long)i*HD;
    float acc = 0.f;
    for (int k=0;k<HD;k+=4){
        float4 wv = *(const float4*)(wr+k);
        float4 lv = *(const float4*)(lr+k);
        acc = fmaf(wv.x,lv.x,acc); acc = fmaf(wv.y,lv.y,acc);
        acc = fmaf(wv.z,lv.z,acc); acc = fmaf(wv.w,lv.w,acc);
    }
    M[(long)j*MLEN + i] = acc;
}

// decoder embedding-side precomputes: APRE[t][a], CPRE[t][j]
__global__ void k_decpre(const float* __restrict__ emb_dec, const int* __restrict__ tgt,
                         const float* __restrict__ attn_w, const float* __restrict__ attn_b,
                         const float* __restrict__ comb_w, const float* __restrict__ comb_b,
                         float* __restrict__ APRE, float* __restrict__ CPRE){
    int idx = blockIdx.x*blockDim.x+threadIdx.x;
    if (idx >= TTGT*MLEN + TTGT*HD) return;
    if (idx < TTGT*MLEN){
        int t = idx/MLEN, a = idx%MLEN;
        int tok = (t==0) ? 1 : tgt[t-1];
        const float* x = emb_dec + (long)tok*HD;
        const float* wr = attn_w + (long)a*1200;
        float acc = attn_b[a];
        for (int k=0;k<HD;k+=4){
            float4 wv = *(const float4*)(wr+k);
            float4 xv = *(const float4*)(x+k);
            acc = fmaf(wv.x,xv.x,acc); acc = fmaf(wv.y,xv.y,acc);
            acc = fmaf(wv.z,xv.z,acc); acc = fmaf(wv.w,xv.w,acc);
        }
        APRE[t*MLEN + a] = acc;
    } else {
        int idx2 = idx - TTGT*MLEN;
        int t = idx2/HD, j = idx2%HD;
        int tok = (t==0) ? 1 : tgt[t-1];
        const float* x = emb_dec + (long)tok*HD;
        const float* wr = comb_w + (long)j*1200;
        float acc = comb_b[j];
        for (int k=0;k<HD;k+=4){
            float4 wv = *(const float4*)(wr+k);
            float4 xv = *(const float4*)(x+k);
            acc = fmaf(wv.x,xv.x,acc); acc = fmaf(wv.y,xv.y,acc);
            acc = fmaf(wv.z,xv.z,acc); acc = fmaf(wv.w,xv.w,acc);
        }
        CPRE[(long)t*HD + j] = acc;
    }
}

// decoder stage A (single block): attention softmax + o = relu(...)
__global__ void __launch_bounds__(512) k_dec_a(const float* __restrict__ attn_w,
        const float* __restrict__ M, const float* __restrict__ apre_t,
        const float* __restrict__ cpre_t, const float* __restrict__ h_prev,
        float* __restrict__ o_out){
    __shared__ float h[HD];
    __shared__ float s[MLEN];
    __shared__ float aw[MLEN];
    int tid = threadIdx.x;
    if (tid < HD) h[tid] = h_prev[tid];
    if (tid+512 < HD) h[tid+512] = h_prev[tid+512];
    __syncthreads();
    int wave = tid>>6, lane = tid&63;
    for (int a=wave; a<MLEN; a+=8){
        const float* wr = attn_w + (long)a*1200 + HD;
        float acc = 0.f;
        for (int k=lane;k<HD;k+=64) acc = fmaf(wr[k], h[k], acc);
        for (int off=32; off; off>>=1) acc += __shfl_xor(acc, off);
        if (lane==0) s[a] = acc + apre_t[a];
    }
    __syncthreads();
    if (tid==0){
        float m = -1e30f;
        for (int a=0;a<MLEN;a++) m = fmaxf(m, s[a]);
        float sum = 0.f;
        for (int a=0;a<MLEN;a++){ float e = __expf(s[a]-m); aw[a]=e; sum+=e; }
        float inv = 1.f/sum;
        for (int a=0;a<MLEN;a++) aw[a] *= inv;
    }
    __syncthreads();
    for (int j=tid;j<HD;j+=512){
        const float* mr = M + (long)j*MLEN;
        float acc = cpre_t[j];
        for (int i=0;i<MLEN;i++) acc = fmaf(mr[i], aw[i], acc);
        o_out[j] = fmaxf(acc, 0.f);
    }
}

// decoder stage B: GRU cells (f,b), 600 outputs, one wave each
__global__ void k_dec_b(const float* __restrict__ wih_f, const float* __restrict__ bih_f,
                        const float* __restrict__ whh_f, const float* __restrict__ bhh_f,
                        const float* __restrict__ wih_b, const float* __restrict__ bih_b,
                        const float* __restrict__ whh_b, const float* __restrict__ bhh_b,
                        const float* __restrict__ o, const float* __restrict__ h_prev,
                        float* __restrict__ h_out){
    int wave = (blockIdx.x*blockDim.x + threadIdx.x)>>6;
    int lane = threadIdx.x & 63;
    if (wave >= HD) return;
    int dir = wave/HHD, k = wave%HHD;
    const float* wih = dir ? wih_b : wih_f;
    const float* bih = dir ? bih_b : bih_f;
    const float* whh = dir ? whh_b : whh_f;
    const float* bhh = dir ? bhh_b : bhh_f;
    float ar=0.f, az=0.f, an=0.f;
    for (int k2=lane;k2<HD;k2+=64){
        float ov = o[k2];
        ar = fmaf(wih[(long)k*HD + k2], ov, ar);
        az = fmaf(wih[(long)(HHD+k)*HD + k2], ov, az);
        an = fmaf(wih[(long)(2*HHD+k)*HD + k2], ov, an);
    }
    float sr=0.f, sz=0.f, sn=0.f;
    const float* hp = h_prev + dir*HHD;
    for (int k2=lane;k2<HHD;k2+=64){
        float hv = hp[k2];
        sr = fmaf(whh[(long)k*HHD + k2], hv, sr);
        sz = fmaf(whh[(long)(HHD+k)*HHD + k2], hv, sz);
        sn = fmaf(whh[(long)(2*HHD+k)*HHD + k2], hv, sn);
    }
    for (int off=32; off; off>>=1){
        ar += __shfl_xor(ar, off); az += __shfl_xor(az, off); an += __shfl_xor(an, off);
        sr += __shfl_xor(sr, off); sz += __shfl_xor(sz, off); sn += __shfl_xor(sn, off);
    }
    if (lane==0){
        float r = sigmoidf_(ar + bih[k]       + sr + bhh[k]);
        float z = sigmoidf_(az + bih[HHD+k]   + sz + bhh[HHD+k]);
        float n = tanhf(an + bih[2*HHD+k] + r*(sn + bhh[2*HHD+k]));
        h_out[dir*HHD + k] = (1.f-z)*n + z*hp[k];
    }
}

// out GEMM: logits[t][v] = dot(out_w[v,:], HS[t,:]) + out_b[v]
// K split in two halves so LDS tile = 50x300 f32 = 60 KB; out_w read exactly once.
__global__ void __launch_bounds__(256) k_out_gemm(const float* __restrict__ out_w,
        const float* __restrict__ out_b, const float* __restrict__ HS,
        float* __restrict__ logits){
    __shared__ float hs[TTGT*HHD]; // 15000 floats
    int v = blockIdx.x*256 + threadIdx.x;
    float acc[TTGT];
    float bv = (v<VSZ) ? out_b[v] : 0.f;
    #pragma unroll
    for (int t=0;t<TTGT;t++) acc[t] = bv;
    for (int half=0; half<2; half++){
        __syncthreads();
        for (int i=threadIdx.x;i<TTGT*HHD;i+=256){
            int t = i/HHD, k = i%HHD;
            hs[i] = HS[t*HD + half*HHD + k];
        }
        __syncthreads();
        if (v < VSZ){
            const float* wr = out_w + (long)v*HD + half*HHD;
            for (int k=0;k<HHD;k+=4){
                float4 w4 = *(const float4*)(wr+k);
                #pragma unroll
                for (int t=0;t<TTGT;t++){
                    float4 h4 = *(const float4*)(&hs[t*HHD+k]);
                    acc[t] = fmaf(w4.x,h4.x,acc[t]); acc[t] = fmaf(w4.y,h4.y,acc[t]);
                    acc[t] = fmaf(w4.z,h4.z,acc[t]); acc[t] = fmaf(w4.w,h4.w,acc[t]);
                }
            }
        }
    }
    if (v < VSZ){
        for (int t=0;t<TTGT;t++) logits[(long)t*VSZ + v] = acc[t];
    }
}

// in-place log-softmax per step row
__global__ void __launch_bounds__(1024) k_lsm(float* __restrict__ logits){
    __shared__ float red[16];
    __shared__ float sm, sl;
    long t = blockIdx.x;
    float* row = logits + t*VSZ;
    int tid = threadIdx.x, lane = tid&63, w = tid>>6;
    float m = -1e30f;
    for (int v=tid;v<VSZ;v+=1024) m = fmaxf(m, row[v]);
    for (int off=32;off;off>>=1) m = fmaxf(m, __shfl_xor(m, off));
    if (lane==0) red[w] = m;
    __syncthreads();
    if (tid==0){ float mm=red[0]; for (int i=1;i<16;i++) mm=fmaxf(mm,red[i]); sm=mm; }
    __syncthreads();
    float mx = sm;
    float s = 0.f;
    for (int v=tid;v<VSZ;v+=1024) s += __expf(row[v]-mx);
    for (int off=32;off;off>>=1) s += __shfl_xor(s, off);
    __syncthreads();
    if (lane==0) red[w] = s;
    __syncthreads();
    if (tid==0){ float ss=0.f; for (int i=0;i<16;i++) ss+=red[i]; sl = logf(ss); }
    __syncthreads();
    float lg = sl;
    for (int v=tid;v<VSZ;v+=1024) row[v] = row[v] - mx - lg;
}

extern "C" void kernel_launch(void* const* d_in, const int* in_sizes, int n_in,
                              void* d_out, int out_size, void* d_ws, size_t ws_size,
                              hipStream_t stream) {
    const float* emb_enc   = (const float*)d_in[0];
    const float* emb_dec   = (const float*)d_in[1];
    const float* enc_wih_f = (const float*)d_in[2];
    const float* enc_whh_f = (const float*)d_in[3];
    const float* enc_bih_f = (const float*)d_in[4];
    const float* enc_bhh_f = (const float*)d_in[5];
    const float* enc_wih_b = (const float*)d_in[6];
    const float* enc_whh_b = (const float*)d_in[7];
    const float* enc_bih_b = (const float*)d_in[8];
    const float* enc_bhh_b = (const float*)d_in[9];
    const float* dec_wih_f = (const float*)d_in[10];
    const float* dec_whh_f = (const float*)d_in[11];
    const float* dec_bih_f = (const float*)d_in[12];
    const float* dec_bhh_f = (const float*)d_in[13];
    const float* dec_wih_b = (const float*)d_in[14];
    const float* dec_whh_b = (const float*)d_in[15];
    const float* dec_bih_b = (const float*)d_in[16];
    const float* dec_bhh_b = (const float*)d_in[17];
    const float* w_mean    = (const float*)d_in[18];
    const float* b_mean    = (const float*)d_in[19];
    const float* w_logv    = (const float*)d_in[20];
    const float* b_logv    = (const float*)d_in[21];
    const float* w_l2h     = (const float*)d_in[22];
    const float* b_l2h     = (const float*)d_in[23];
    const float* attn_w    = (const float*)d_in[24];
    const float* attn_b    = (const float*)d_in[25];
    const float* comb_w    = (const float*)d_in[26];
    const float* comb_b    = (const float*)d_in[27];
    const float* out_w     = (const float*)d_in[28];
    const float* out_b     = (const float*)d_in[29];
    const float* eps       = (const float*)d_in[30];
    const int*   in_toks   = (const int*)d_in[31];
    const int*   tgt_toks  = (const int*)d_in[32];

    float* ws   = (float*)d_ws;
    float* GI   = ws;              // 48*1800 = 86400
    float* ENC  = ws + 86400;      // 50*600  = 30000
    float* Z    = ws + 116400;     // 5000
    float* LATo = ws + 121400;     // 30000
    float* M    = ws + 151400;     // 30000
    float* APRE = ws + 181400;     // 2500
    float* CPRE = ws + 183900;     // 30000
    float* O    = ws + 213904;     // 600
    float* HS   = ws + 214504;     // 30000

    float* dec_out  = (float*)d_out;            // 50*50000 logits -> logp (in place)
    float* out_mean = dec_out + 2500000;        // 5000
    float* out_logv = dec_out + 2505000;        // 5000

    // zero padded encoder rows 48,49
    k_zero<<<5, 256, 0, stream>>>(ENC + TIN*HD, (MLEN-TIN)*HD);

    // encoder input-gate precompute
    k_enc_gi<<<(TIN*1800+255)/256, 256, 0, stream>>>(emb_enc, in_toks,
        enc_wih_f, enc_bih_f, enc_wih_b, enc_bih_b, GI);

    // encoder recurrence
    for (int t=0;t<TIN;t++){
        k_enc_step<<<150, 256, 0, stream>>>(enc_whh_f, enc_bhh_f, enc_whh_b, enc_bhh_b,
            GI + (long)t*1800, t ? (ENC + (long)(t-1)*HD) : nullptr, ENC + (long)t*HD);
    }

    // latent path
    k_meanlogv<<<(2*MLEN*LATD+255)/256, 256, 0, stream>>>(ENC, w_mean, b_mean, w_logv, b_logv,
        out_mean, out_logv);
    k_z<<<(MLEN*LATD+255)/256, 256, 0, stream>>>(eps, out_logv, out_mean, Z);
    k_latent<<<(MLEN*HD+255)/256, 256, 0, stream>>>(Z, w_l2h, b_l2h, LATo);
    k_mcomb<<<(HD*MLEN+255)/256, 256, 0, stream>>>(comb_w, LATo, M);

    // decoder embedding-side precompute
    k_decpre<<<(TTGT*MLEN + TTGT*HD + 255)/256, 256, 0, stream>>>(emb_dec, tgt_toks,
        attn_w, attn_b, comb_w, comb_b, APRE, CPRE);

    // decoder recurrence
    for (int t=0;t<TTGT;t++){
        const float* hp = t ? (HS + (long)(t-1)*HD) : (ENC + (long)47*HD);
        k_dec_a<<<1, 512, 0, stream>>>(attn_w, M, APRE + t*MLEN, CPRE + (long)t*HD, hp, O);
        k_dec_b<<<150, 256, 0, stream>>>(dec_wih_f, dec_bih_f, dec_whh_f, dec_bhh_f,
            dec_wih_b, dec_bih_b, dec_whh_b, dec_bhh_b, O, hp, HS + (long)t*HD);
    }

    // vocab projection + log-softmax
    k_out_gemm<<<(VSZ+255)/256, 256, 0, stream>>>(out_w, out_b, HS, dec_out);
    k_lsm<<<TTGT, 1024, 0, stream>>>(dec_out);
}